// Round 10
// baseline (87.831 us; speedup 1.0000x reference)
//
#include <hip/hip_runtime.h>

typedef _Float16 half2_t __attribute__((ext_vector_type(2)));
typedef _Float16 half4_t __attribute__((ext_vector_type(4)));
typedef _Float16 half8_t __attribute__((ext_vector_type(8)));
typedef float    f32x4   __attribute__((ext_vector_type(4)));

#define S_LEN 2048
#define DH    64
#define QBLK  64    // q rows per block (4 waves x 16)
#define KVB   64    // kv rows per tile
#define NQB   32    // q-blocks; block handles pair (pb, 31-pb) -> 33 tiles
// (1/sqrt(1024)) * log2(e): softmax in exp2 domain
#define SCALE 0.045110910340389066f
#define DEFER_THR 8.0f   // T13: P bounded by 2^8, f16-safe

// XOR-swizzle for [row][128B] LDS tiles (m214 r268).
__device__ __forceinline__ int swz_off(int row, int byteInRow) {
    return row * 128 + (byteInRow ^ ((row & 7) << 4));
}
// V^T tile swizzle: extra bit-3 key -> b64 writes and reads at width floor.
__device__ __forceinline__ int vswz(int row, int byteInRow) {
    return row * 128 + (byteInRow ^ ((row & 7) << 4) ^ (row & 8));
}

__device__ __forceinline__ half4_t cvt4(f32x4 x) {
    half2_t a = __builtin_bit_cast(half2_t, __builtin_amdgcn_cvt_pkrtz(x[0], x[1]));
    half2_t b = __builtin_bit_cast(half2_t, __builtin_amdgcn_cvt_pkrtz(x[2], x[3]));
    half4_t r; r[0] = a[0]; r[1] = a[1]; r[2] = b[0]; r[3] = b[1];
    return r;
}
__device__ __forceinline__ float fmax3(float a, float b, float c) {
    return fmaxf(fmaxf(a, b), c);   // fuses to v_max3_f32
}

__global__ __launch_bounds__(256, 4)
void fattn_kernel(const float* __restrict__ Qg, const float* __restrict__ Kg,
                  const float* __restrict__ Vg, float* __restrict__ Og) {
    __shared__ __align__(16) char smem[32768];   // 2 x (K 8KB + V^T 8KB)

    const int bh  = (int)blockIdx.x;     // 0..63
    const int pb  = (int)blockIdx.y;     // 0..15 -> pair (pb, 31-pb)
    const int tid = (int)threadIdx.x;
    const int lane = tid & 63;
    const int w    = tid >> 6;           // wave 0..3
    const int c    = lane & 15;
    const int g    = lane >> 4;

    const size_t base = (size_t)bh * S_LEN * DH;
    const float* Qp = Qg + base;
    const float* Kp = Kg + base;
    const float* Vp = Vg + base;
    float*       Op = Og + base;

    // ---- staging task split: waves 0-1 stage K, waves 2-3 stage V ----
    const bool isK = tid < 128;
    const int sid = tid & 127;
    const int r0  = sid >> 4;            // K row 0..7 (+8 per i)
    const int c4  = (sid & 15) << 2;     // K f32 col
    const int kLds0 = swz_off(r0, c4 * 2);   // +i*1024
    const int kq4 = (sid >> 4) << 2;     // V k-quad 0..28 (+32 for h=1)
    const int d4  = (sid & 15) << 2;     // V d col 0..60

    f32x4 pr[8];   // staging registers (32 VGPR, held across compute)
    auto stage_load = [&](int kv) {
        if (isK) {
#pragma unroll
            for (int i = 0; i < 8; ++i)
                pr[i] = *(const f32x4*)(Kp + (size_t)((kv + r0 + 8 * i) * DH + c4));
        } else {
#pragma unroll
            for (int h = 0; h < 2; ++h)
#pragma unroll
                for (int j = 0; j < 4; ++j)
                    pr[h * 4 + j] = *(const f32x4*)(Vp + (size_t)((kv + kq4 + 32 * h + j) * DH + d4));
        }
    };
    auto stage_write = [&](char* buf) {
        if (isK) {
#pragma unroll
            for (int i = 0; i < 8; ++i)
                *(half4_t*)(buf + kLds0 + i * 1024) = cvt4(pr[i]);
        } else {
            char* Vw = buf + 8192;
#pragma unroll
            for (int h = 0; h < 2; ++h)
#pragma unroll
                for (int jj = 0; jj < 4; ++jj) {   // 4x4 transpose via subreg packs
                    half2_t lo = __builtin_bit_cast(half2_t, __builtin_amdgcn_cvt_pkrtz(pr[h*4+0][jj], pr[h*4+1][jj]));
                    half2_t hi = __builtin_bit_cast(half2_t, __builtin_amdgcn_cvt_pkrtz(pr[h*4+2][jj], pr[h*4+3][jj]));
                    half4_t col; col[0] = lo[0]; col[1] = lo[1]; col[2] = hi[0]; col[3] = hi[1];
                    *(half4_t*)(Vw + vswz(d4 + jj, (kq4 + 32 * h) * 2)) = col;
                }
        }
    };

    for (int phase = 0; phase < 2; ++phase) {
        const int qb = phase ? (NQB - 1 - pb) : pb;
        const int q0 = qb * QBLK;
        const int qrow = q0 + w * 16;    // wave's 16 q rows
        const int nT = qb + 1;           // causal tiles for this q-block

        // ---- Q fragments (scaled into exp2 domain) ----
        half8_t qf0, qf1;
        {
            const float* qptr = Qp + (size_t)(qrow + c) * DH;
#pragma unroll
            for (int s = 0; s < 2; ++s) {
                f32x4 a = *(const f32x4*)(qptr + s * 32 + g * 8);
                f32x4 b = *(const f32x4*)(qptr + s * 32 + g * 8 + 4);
                half8_t h;
#pragma unroll
                for (int j = 0; j < 4; ++j) {
                    h[j]     = (_Float16)(a[j] * SCALE);
                    h[j + 4] = (_Float16)(b[j] * SCALE);
                }
                if (s == 0) qf0 = h; else qf1 = h;
            }
        }

        f32x4 oacc[4];   // O^T: d = 16*dt + 4g + r, q = qrow + c
#pragma unroll
        for (int dt = 0; dt < 4; ++dt) oacc[dt] = (f32x4){0.f, 0.f, 0.f, 0.f};
        float nm = 0.f;      // NEGATED running max (m init 0: safe reference)
        float l_run = 0.f;   // per-lane partial, scaled by 2^-m

        // ---- prologue: stage tile 0 (loads before the phase barrier) ----
        stage_load(0);
        if (phase) __syncthreads();   // prior phase's readers done before rewrite
        stage_write(smem);

        int cur = 0;
        for (int t = 0; t < nT; ++t) {
            __syncthreads();   // buf[cur] written; prior reads of buf[cur^1] done
            const bool pf = (t + 1 < nT);
            if (pf) stage_load((t + 1) * KVB);   // issue-early

            char* const Ks = smem + cur * 16384;
            char* const Vs = Ks + 8192;

            // ---- QK^T swapped, C-init = -m: st = S_raw - m after MFMA ----
            const f32x4 mi = (f32x4){nm, nm, nm, nm};
            f32x4 st[4];
#pragma unroll
            for (int kt = 0; kt < 4; ++kt) st[kt] = mi;
            __builtin_amdgcn_s_setprio(1);
#pragma unroll
            for (int kt = 0; kt < 4; ++kt) {
                half8_t kf0 = *(const half8_t*)(Ks + swz_off(kt * 16 + c, g * 16));
                half8_t kf1 = *(const half8_t*)(Ks + swz_off(kt * 16 + c, 64 + g * 16));
                st[kt] = __builtin_amdgcn_mfma_f32_16x16x32_f16(kf0, qf0, st[kt], 0, 0, 0);
                st[kt] = __builtin_amdgcn_mfma_f32_16x16x32_f16(kf1, qf1, st[kt], 0, 0, 0);
            }
            __builtin_amdgcn_s_setprio(0);

            // ---- causal mask: only the diagonal (last) tile ----
            if (t == nT - 1) {
                const int kv0 = t * KVB;
                const int qq = qrow + c;
#pragma unroll
                for (int kt = 0; kt < 4; ++kt)
#pragma unroll
                    for (int r = 0; r < 4; ++r)
                        if (kv0 + kt * 16 + g * 4 + r > qq) st[kt][r] = -1e30f;
            }

            // ---- online softmax (exp2), vote-gated rescale ----
            float m0 = fmax3(st[0][0], st[0][1], st[0][2]);
            float m1 = fmax3(st[0][3], st[1][0], st[1][1]);
            float m2 = fmax3(st[1][2], st[1][3], st[2][0]);
            float m3 = fmax3(st[2][1], st[2][2], st[2][3]);
            float m4 = fmax3(st[3][0], st[3][1], st[3][2]);
            float tmax = fmaxf(fmax3(fmax3(m0, m1, m2), m3, m4), st[3][3]);
            if (!__all(tmax <= DEFER_THR)) {   // tmax is already S_raw - m
                float tr = fmaxf(tmax, __shfl_xor(tmax, 16));
                tr = fmaxf(tr, __shfl_xor(tr, 32));
                const float delta = fmaxf(tr, 0.f);
                const float alpha = __builtin_amdgcn_exp2f(-delta);
                nm -= delta;
                l_run *= alpha;
#pragma unroll
                for (int dt = 0; dt < 4; ++dt) oacc[dt] = oacc[dt] * alpha;
#pragma unroll
                for (int kt = 0; kt < 4; ++kt) st[kt] = st[kt] - delta;
            }
            float tsum = 0.f;
            half4_t pfq[4];   // P^T f16, already in PV B-fragment layout
#pragma unroll
            for (int kt = 0; kt < 4; ++kt) {
#pragma unroll
                for (int r = 0; r < 4; ++r) {
                    float p = __builtin_amdgcn_exp2f(st[kt][r]);
                    tsum += p;
                    st[kt][r] = p;
                }
                pfq[kt] = cvt4(st[kt]);
            }
            l_run += tsum;

            // ---- PV: O^T += V^T . P^T via 16x16x16 f16 ----
            __builtin_amdgcn_s_setprio(1);
#pragma unroll
            for (int ks = 0; ks < 4; ++ks) {
                half4_t vf[4];
#pragma unroll
                for (int dt = 0; dt < 4; ++dt)  // A: V^T[16dt+c][16ks+4g+j]
                    vf[dt] = *(const half4_t*)(Vs + vswz(dt * 16 + c, ks * 32 + g * 8));
#pragma unroll
                for (int dt = 0; dt < 4; ++dt)
                    oacc[dt] = __builtin_amdgcn_mfma_f32_16x16x16f16(vf[dt], pfq[ks], oacc[dt], 0, 0, 0);
            }
            __builtin_amdgcn_s_setprio(0);

            if (pf) stage_write(smem + (cur ^ 1) * 16384);   // write-late
            cur ^= 1;
        }

        // ---- epilogue: reduce l across g-groups, normalize, store ----
        float lr = l_run;
        lr += __shfl_xor(lr, 16);
        lr += __shfl_xor(lr, 32);
        const float inv = __builtin_amdgcn_rcpf(lr);
        float* optr = Op + (size_t)(qrow + c) * DH;
#pragma unroll
        for (int dt = 0; dt < 4; ++dt) {
            f32x4 o = oacc[dt] * inv;
            *(f32x4*)(optr + dt * 16 + g * 4) = o;
        }
    }
}

extern "C" void kernel_launch(void* const* d_in, const int* in_sizes, int n_in,
                              void* d_out, int out_size, void* d_ws, size_t ws_size,
                              hipStream_t stream) {
    (void)in_sizes; (void)n_in; (void)out_size; (void)d_ws; (void)ws_size;
    const float* Q = (const float*)d_in[0];
    const float* K = (const float*)d_in[1];
    const float* V = (const float*)d_in[2];
    float* O = (float*)d_out;
    dim3 grid(64, NQB / 2);   // 1024 balanced blocks (33 tiles each), 4/CU
    fattn_kernel<<<grid, 256, 0, stream>>>(Q, K, V, O);
}

// Round 11
// 67.376 us; speedup vs baseline: 1.3036x; 1.3036x over previous
//
#include <hip/hip_runtime.h>

typedef _Float16 half2_t __attribute__((ext_vector_type(2)));
typedef _Float16 half4_t __attribute__((ext_vector_type(4)));
typedef _Float16 half8_t __attribute__((ext_vector_type(8)));
typedef float    f32x4   __attribute__((ext_vector_type(4)));
typedef unsigned int u32x4 __attribute__((ext_vector_type(4)));

#define S_LEN 2048
#define DH    64
#define QBLK  128   // q rows per block (8 waves x 16)
#define KVB   64    // kv rows per tile
#define NQB   16
// (1/sqrt(1024)) * log2(e): softmax in exp2 domain
#define SCALE 0.045110910340389066f
#define DEFER_THR 8.0f   // T13: P bounded by 2^8, f16-safe

// XOR-swizzle for [row][128B] LDS tiles, 16B atoms (m214 r268).
__device__ __forceinline__ int swz_off(int row, int byteInRow) {
    return row * 128 + (byteInRow ^ ((row & 7) << 4));
}

__device__ __forceinline__ half4_t cvt4(f32x4 x) {
    half2_t a = __builtin_bit_cast(half2_t, __builtin_amdgcn_cvt_pkrtz(x[0], x[1]));
    half2_t b = __builtin_bit_cast(half2_t, __builtin_amdgcn_cvt_pkrtz(x[2], x[3]));
    half4_t r; r[0] = a[0]; r[1] = a[1]; r[2] = b[0]; r[3] = b[1];
    return r;
}
__device__ __forceinline__ unsigned int pk2(float a, float b) {
    return __builtin_bit_cast(unsigned int, __builtin_amdgcn_cvt_pkrtz(a, b));
}
__device__ __forceinline__ float fmax3(float a, float b, float c) {
    return fmaxf(fmaxf(a, b), c);   // fuses to v_max3_f32
}

__global__ __launch_bounds__(512, 4)
void fattn_kernel(const float* __restrict__ Qg, const float* __restrict__ Kg,
                  const float* __restrict__ Vg, float* __restrict__ Og) {
    __shared__ __align__(16) char smem[32768];   // 2 x (K 8KB + V^T 8KB)

    const int bh  = (int)blockIdx.x;                 // 0..63
    const int qb  = (NQB - 1) - (int)blockIdx.y;     // heavy-first
    const int q0  = qb * QBLK;
    const int tid = (int)threadIdx.x;
    const int lane = tid & 63;
    const int w    = tid >> 6;           // wave 0..7
    const int c    = lane & 15;
    const int g    = lane >> 4;

    const size_t base = (size_t)bh * S_LEN * DH;
    const float* Qp = Qg + base;
    const float* Kp = Kg + base;
    const float* Vp = Vg + base;
    float*       Op = Og + base;

    const int qrow = q0 + w * 16;        // wave's 16 q rows
    const int nT = 2 * qb + 2;           // kv tiles for this q-block

    // ---- staging task split: waves 0-3 stage K, waves 4-7 stage V ----
    const bool isK = tid < 256;
    const int sid = tid & 255;
    const int r0  = sid >> 4;            // K row 0..15 (+16 per i)
    const int c4  = (sid & 15) << 2;     // K f32 col
    const int kLds0 = swz_off(r0, c4 * 2);   // +i*2048
    const int kq4 = (sid >> 4) << 2;     // V k-quad 0..60
    const int d4  = (sid & 15) << 2;     // V d col 0..60
    // sigma-permuted V column byte: within each 32-k chunk, k-quad kqc maps to
    // position-quad 2*kqc (kqc<16) or 2*kqc-28 (kqc>=16), so PV's x32 A-operand
    // slot order 8g+j matches P's natural QK-output order 4g+r / 16+4g+r.
    const int kqc = kq4 & 31;
    const int vColByte = ((kqc < 16) ? (4 * kqc) : (4 * kqc - 56)) + ((kq4 & 32) << 1);

    // ---- Q fragments (scaled into exp2 domain) ----
    half8_t qf0, qf1;
    {
        const float* qptr = Qp + (size_t)(qrow + c) * DH;
#pragma unroll
        for (int s = 0; s < 2; ++s) {
            f32x4 a = *(const f32x4*)(qptr + s * 32 + g * 8);
            f32x4 b = *(const f32x4*)(qptr + s * 32 + g * 8 + 4);
            half8_t h;
#pragma unroll
            for (int j = 0; j < 4; ++j) {
                h[j]     = (_Float16)(a[j] * SCALE);
                h[j + 4] = (_Float16)(b[j] * SCALE);
            }
            if (s == 0) qf0 = h; else qf1 = h;
        }
    }

    f32x4 oacc[4];   // O^T: d = 16*dt + 4g + r, q = qrow + c
#pragma unroll
    for (int dt = 0; dt < 4; ++dt) oacc[dt] = (f32x4){0.f, 0.f, 0.f, 0.f};
    float nm = 0.f;      // NEGATED running max (init 0: valid reference)
    float l_run = 0.f;   // per-lane partial of sum 2^(S-m)

    // ---- staging helpers (role-specific, 4 f32x4 regs) ----
    f32x4 pr[4];
    auto stage_load = [&](int kv) {
        if (isK) {
#pragma unroll
            for (int i = 0; i < 4; ++i)
                pr[i] = *(const f32x4*)(Kp + (size_t)((kv + r0 + 16 * i) * DH + c4));
        } else {
#pragma unroll
            for (int j = 0; j < 4; ++j)
                pr[j] = *(const f32x4*)(Vp + (size_t)((kv + kq4 + j) * DH + d4));
        }
    };
    auto stage_write = [&](char* buf) {
        if (isK) {
#pragma unroll
            for (int i = 0; i < 4; ++i)
                *(half4_t*)(buf + kLds0 + i * 2048) = cvt4(pr[i]);
        } else {
            char* Vw = buf + 8192;
#pragma unroll
            for (int jj = 0; jj < 4; ++jj) {   // 4x4 transpose via subreg packs
                half2_t lo = __builtin_bit_cast(half2_t, __builtin_amdgcn_cvt_pkrtz(pr[0][jj], pr[1][jj]));
                half2_t hi = __builtin_bit_cast(half2_t, __builtin_amdgcn_cvt_pkrtz(pr[2][jj], pr[3][jj]));
                half4_t col; col[0] = lo[0]; col[1] = lo[1]; col[2] = hi[0]; col[3] = hi[1];
                *(half4_t*)(Vw + swz_off(d4 + jj, vColByte)) = col;
            }
        }
    };

    // ---- prologue: stage tile 0 into buffer 0 ----
    stage_load(0);
    stage_write(smem);

    int cur = 0;
    for (int t = 0; t < nT; ++t) {
        __syncthreads();   // buf[cur] written; prior reads of buf[cur^1] done
        const bool pf = (t + 1 < nT);
        if (pf) stage_load((t + 1) * KVB);   // issue-early: overlap compute

        const int kv0 = t * KVB;
        char* const Ks = smem + cur * 16384;
        char* const Vs = Ks + 8192;

        if (kv0 <= qrow + 15) {   // wave-uniform: skip fully-masked tiles
            // ---- QK^T swapped, C-init = -m: st = S_raw - m after MFMA ----
            f32x4 st[4];
#pragma unroll
            for (int kt = 0; kt < 4; ++kt) st[kt] = (f32x4){nm, nm, nm, nm};
            __builtin_amdgcn_s_setprio(1);
#pragma unroll
            for (int kt = 0; kt < 4; ++kt) {
                half8_t kf0 = *(const half8_t*)(Ks + swz_off(kt * 16 + c, g * 16));
                half8_t kf1 = *(const half8_t*)(Ks + swz_off(kt * 16 + c, 64 + g * 16));
                st[kt] = __builtin_amdgcn_mfma_f32_16x16x32_f16(kf0, qf0, st[kt], 0, 0, 0);
                st[kt] = __builtin_amdgcn_mfma_f32_16x16x32_f16(kf1, qf1, st[kt], 0, 0, 0);
            }
            __builtin_amdgcn_s_setprio(0);

            // ---- causal mask: tiles overlapping the diagonal ----
            if (kv0 + KVB - 1 > qrow) {
                const int qq = qrow + c;
#pragma unroll
                for (int kt = 0; kt < 4; ++kt)
#pragma unroll
                    for (int r = 0; r < 4; ++r)
                        if (kv0 + kt * 16 + g * 4 + r > qq) st[kt][r] = -1e30f;
            }

            // ---- online softmax (exp2), vote-gated rescale ----
            float m0 = fmax3(st[0][0], st[0][1], st[0][2]);
            float m1 = fmax3(st[0][3], st[1][0], st[1][1]);
            float m2 = fmax3(st[1][2], st[1][3], st[2][0]);
            float m3 = fmax3(st[2][1], st[2][2], st[2][3]);
            float m4 = fmax3(st[3][0], st[3][1], st[3][2]);
            float tmax = fmaxf(fmax3(fmax3(m0, m1, m2), m3, m4), st[3][3]);
            if (!__all(tmax <= DEFER_THR)) {   // tmax is already S_raw - m
                float tr = fmaxf(tmax, __shfl_xor(tmax, 16));
                tr = fmaxf(tr, __shfl_xor(tr, 32));
                const float delta = fmaxf(tr, 0.f);
                const float alpha = __builtin_amdgcn_exp2f(-delta);
                nm -= delta;
                l_run *= alpha;
#pragma unroll
                for (int dt = 0; dt < 4; ++dt) oacc[dt] = oacc[dt] * alpha;
#pragma unroll
                for (int kt = 0; kt < 4; ++kt) st[kt] = st[kt] - delta;
            }
            float tsum = 0.f;
            unsigned int pw[8];   // packed f16 P, QK-native k order
#pragma unroll
            for (int kt = 0; kt < 4; ++kt) {
#pragma unroll
                for (int r = 0; r < 4; ++r) {
                    float p = __builtin_amdgcn_exp2f(st[kt][r]);
                    tsum += p;
                    st[kt][r] = p;
                }
                pw[2 * kt]     = pk2(st[kt][0], st[kt][1]);
                pw[2 * kt + 1] = pk2(st[kt][2], st[kt][3]);
            }
            l_run += tsum;
            const half8_t ph0 = __builtin_bit_cast(half8_t, (u32x4){pw[0], pw[1], pw[2], pw[3]});
            const half8_t ph1 = __builtin_bit_cast(half8_t, (u32x4){pw[4], pw[5], pw[6], pw[7]});

            // ---- PV: O^T += V~ . P via 16x16x32 f16 (sigma-permuted V) ----
            __builtin_amdgcn_s_setprio(1);
#pragma unroll
            for (int dt = 0; dt < 4; ++dt) {
                half8_t vf = *(const half8_t*)(Vs + swz_off(dt * 16 + c, g * 16));
                oacc[dt] = __builtin_amdgcn_mfma_f32_16x16x32_f16(vf, ph0, oacc[dt], 0, 0, 0);
            }
#pragma unroll
            for (int dt = 0; dt < 4; ++dt) {
                half8_t vf = *(const half8_t*)(Vs + swz_off(dt * 16 + c, 64 + g * 16));
                oacc[dt] = __builtin_amdgcn_mfma_f32_16x16x32_f16(vf, ph1, oacc[dt], 0, 0, 0);
            }
            __builtin_amdgcn_s_setprio(0);
        }

        if (pf) stage_write(smem + (cur ^ 1) * 16384);   // write-late
        cur ^= 1;
    }

    // ---- epilogue: reduce l across g-groups, normalize, store ----
    l_run += __shfl_xor(l_run, 16);
    l_run += __shfl_xor(l_run, 32);
    const float inv = __builtin_amdgcn_rcpf(l_run);
    float* optr = Op + (size_t)(qrow + c) * DH;
#pragma unroll
    for (int dt = 0; dt < 4; ++dt) {
        f32x4 o = oacc[dt] * inv;
        *(f32x4*)(optr + dt * 16 + g * 4) = o;
    }
}

extern "C" void kernel_launch(void* const* d_in, const int* in_sizes, int n_in,
                              void* d_out, int out_size, void* d_ws, size_t ws_size,
                              hipStream_t stream) {
    (void)in_sizes; (void)n_in; (void)out_size; (void)d_ws; (void)ws_size;
    const float* Q = (const float*)d_in[0];
    const float* K = (const float*)d_in[1];
    const float* V = (const float*)d_in[2];
    float* O = (float*)d_out;
    dim3 grid(64, NQB);   // 1024 blocks -> 4 blocks/CU, heavy-first in y
    fattn_kernel<<<grid, 512, 0, stream>>>(Q, K, V, O);
}